// Round 1
// baseline (641.025 us; speedup 1.0000x reference)
//
#include <hip/hip_runtime.h>
#include <math.h>

// ConvCapsule fused kernel: 5x5 SAME conv (im2col-per-pixel in LDS) + 3-iter
// dynamic routing entirely in LDS. One 256-thread block per (b,h,w) pixel.
//
// Shapes:
//   x       : [B*32, 8, 32, 32]  (N=256, C=8, H=W=32) fp32
//   conv_w  : [5, 5, 8, 256]     (HWIO) fp32
//   conv_b  : [256]              fp32 (zeros, but applied anyway)
//   biases  : [32, 8]            fp32
//   out     : [8, 32*32*32, 8]   fp32 = act[b, o, h, w, a]

constexpr int IN_DIM  = 32;
constexpr int OUT_DIM = 32;
constexpr int IN_AT   = 8;
constexpr int OUT_AT  = 8;
constexpr int OAC     = OUT_DIM * OUT_AT;   // 256 conv output channels
constexpr int KK      = 5;

__global__ __launch_bounds__(256, 2)
void capsule_fused(const float* __restrict__ x,
                   const float* __restrict__ conv_w,
                   const float* __restrict__ conv_b,
                   const float* __restrict__ biases,
                   float* __restrict__ out)
{
    __shared__ float votes[IN_DIM][OAC];              // 32 KB  votes[i][o*8+a]
    __shared__ float wsl[IN_AT][OAC];                 //  8 KB  weight slice for one (ky,kx)
    __shared__ float xpatch[KK*KK][IN_AT][IN_DIM];    // 25.6KB xpatch[p][ci][i]
    __shared__ float route_s[IN_DIM][OUT_DIM];        //  4 KB
    __shared__ float logits_s[IN_DIM][OUT_DIM];       //  4 KB

    const int t   = threadIdx.x;
    const int blk = blockIdx.x;
    const int b   = blk >> 10;      // 8 batches
    const int pix = blk & 1023;     // h*32+w
    const int h   = pix >> 5;
    const int w   = pix & 31;

    // ---- init routing state ----
    for (int idx = t; idx < IN_DIM * OUT_DIM; idx += 256) {
        logits_s[idx >> 5][idx & 31] = 0.f;
        route_s [idx >> 5][idx & 31] = 1.f / 33.f;   // softmax of 33 zeros (leak + 32)
    }

    // ---- stage x patch (zero-padded SAME window) ----
    for (int idx = t; idx < KK * KK * IN_AT * IN_DIM; idx += 256) {
        const int i  = idx & 31;
        const int ci = (idx >> 5) & 7;
        const int p  = idx >> 8;            // 0..24 (ky*5+kx)
        const int ky = p / 5;
        const int kx = p - ky * 5;
        const int y  = h + ky - 2;
        const int xx = w + kx - 2;
        float v = 0.f;
        if ((unsigned)y < 32u && (unsigned)xx < 32u)
            v = x[(((b * IN_DIM + i) * IN_AT + ci) << 10) + (y << 5) + xx];
        xpatch[p][ci][i] = v;
    }

    // ---- per-pixel conv: thread t owns i in [ig,ig+4), oa in [oc,oc+8) ----
    const int ig = (t & 7) << 2;    // i base
    const int oc = (t >> 3) << 3;   // oa base

    float acc[4][8];
    #pragma unroll
    for (int di = 0; di < 4; ++di)
        #pragma unroll
        for (int j = 0; j < 8; ++j)
            acc[di][j] = conv_b[oc + j];

    __syncthreads();   // xpatch + routing-state init visible

    for (int p = 0; p < 25; ++p) {
        // stage weights for this tap: wsl[ci][oa]
        #pragma unroll
        for (int ci = 0; ci < 8; ++ci)
            wsl[ci][t] = conv_w[(p * 8 + ci) * 256 + t];
        __syncthreads();
        #pragma unroll
        for (int ci = 0; ci < 8; ++ci) {
            const float4 xv = *(const float4*)&xpatch[p][ci][ig];
            const float4 w0 = *(const float4*)&wsl[ci][oc];
            const float4 w1 = *(const float4*)&wsl[ci][oc + 4];
            const float xa[4] = {xv.x, xv.y, xv.z, xv.w};
            const float wa[8] = {w0.x, w0.y, w0.z, w0.w, w1.x, w1.y, w1.z, w1.w};
            #pragma unroll
            for (int di = 0; di < 4; ++di)
                #pragma unroll
                for (int j = 0; j < 8; ++j)
                    acc[di][j] = fmaf(xa[di], wa[j], acc[di][j]);
        }
        __syncthreads();   // before overwriting wsl next tap
    }

    // ---- votes -> LDS ----
    #pragma unroll
    for (int di = 0; di < 4; ++di) {
        const float4 v0 = {acc[di][0], acc[di][1], acc[di][2], acc[di][3]};
        const float4 v1 = {acc[di][4], acc[di][5], acc[di][6], acc[di][7]};
        *(float4*)&votes[ig + di][oc]     = v0;
        *(float4*)&votes[ig + di][oc + 4] = v1;
    }
    __syncthreads();

    // ---- routing: thread t owns output (o_t, a_t) ----
    const int o_t = t >> 3;
    const int a_t = t & 7;
    const float bias_v = biases[t];     // biases[o][a] flat == t
    float actv = 0.f;

    for (int it = 0; it < 3; ++it) {
        if (it > 0) {
            // leaky softmax per row i: 8 lanes per row, 4 o's each
            const int r = t >> 3, sub = t & 7;
            float e0 = logits_s[r][sub * 4 + 0];
            float e1 = logits_s[r][sub * 4 + 1];
            float e2 = logits_s[r][sub * 4 + 2];
            float e3 = logits_s[r][sub * 4 + 3];
            float mx = fmaxf(fmaxf(e0, e1), fmaxf(e2, e3));
            mx = fmaxf(mx, 0.f);   // leak logit
            #pragma unroll
            for (int d = 1; d < 8; d <<= 1)
                mx = fmaxf(mx, __shfl_xor(mx, d));
            e0 = expf(e0 - mx); e1 = expf(e1 - mx);
            e2 = expf(e2 - mx); e3 = expf(e3 - mx);
            float ssum = e0 + e1 + e2 + e3;
            #pragma unroll
            for (int d = 1; d < 8; d <<= 1)
                ssum += __shfl_xor(ssum, d);
            const float inv = 1.f / (ssum + expf(0.f - mx));
            route_s[r][sub * 4 + 0] = e0 * inv;
            route_s[r][sub * 4 + 1] = e1 * inv;
            route_s[r][sub * 4 + 2] = e2 * inv;
            route_s[r][sub * 4 + 3] = e3 * inv;
        }
        __syncthreads();

        // preact[o_t][a_t] = sum_i votes[i][t] * route[i][o_t] + bias
        float s = bias_v;
        #pragma unroll
        for (int i = 0; i < 32; ++i)
            s = fmaf(votes[i][t], route_s[i][o_t], s);

        // squash over the 8-atom group (lanes t&7)
        float ns = s * s;
        #pragma unroll
        for (int d = 1; d < 8; d <<= 1)
            ns += __shfl_xor(ns, d);
        const float norm = sqrtf(ns);
        actv = s * norm / (1.f + ns);    // (s/n)*(n^2/(1+n^2))

        if (it < 2) {
            // logits[i][o] += sum_a votes[i][o][a] * act[o][a]
            #pragma unroll
            for (int i = 0; i < 32; ++i) {
                float d = votes[i][t] * actv;
                d += __shfl_xor(d, 1);
                d += __shfl_xor(d, 2);
                d += __shfl_xor(d, 4);
                if (a_t == 0) logits_s[i][o_t] += d;
            }
            __syncthreads();
        }
    }

    // out[b][o][h][w][a]
    out[((((b * OUT_DIM + o_t) << 10) + pix) << 3) + a_t] = actv;
}

extern "C" void kernel_launch(void* const* d_in, const int* in_sizes, int n_in,
                              void* d_out, int out_size, void* d_ws, size_t ws_size,
                              hipStream_t stream) {
    const float* x      = (const float*)d_in[0];
    const float* conv_w = (const float*)d_in[1];
    const float* conv_b = (const float*)d_in[2];
    const float* biases = (const float*)d_in[3];
    float* out = (float*)d_out;
    hipLaunchKernelGGL(capsule_fused, dim3(8 * 32 * 32), dim3(256), 0, stream,
                       x, conv_w, conv_b, biases, out);
}

// Round 2
// 186.269 us; speedup vs baseline: 3.4414x; 3.4414x over previous
//
#include <hip/hip_runtime.h>
#include <math.h>

// ConvCapsule: bf16-MFMA per-pixel conv + fused 3-iter dynamic routing.
// prep_w: conv_w fp32 -> bf16 in ws, layout [s(7)][g(4)][oa(256)][j(8)]
// prep_x: x fp32 -> bf16 in ws, layout [b][y][x][i*8+ci]  (4 MB)
// main:   one 256-thread block per (b,h,w) pixel; votes via MFMA; routing in LDS.

using short8 = __attribute__((ext_vector_type(8))) short;
using f32x4  = __attribute__((ext_vector_type(4))) float;

__device__ __forceinline__ unsigned short f2bf(float f) {
    unsigned u = __float_as_uint(f);
    return (unsigned short)((u + 0x7fffu + ((u >> 16) & 1u)) >> 16);  // RNE
}

// ---------- prep 1: W -> bf16, [s][g][oa][j], k = s*32+g*8+j ----------
__global__ __launch_bounds__(256)
void prep_w(const float* __restrict__ cw, unsigned short* __restrict__ wp) {
    const int idx = blockIdx.x * 256 + threadIdx.x;   // 57344 total
    const int j  = idx & 7;
    const int oa = (idx >> 3) & 255;
    const int g  = (idx >> 11) & 3;
    const int s  = idx >> 13;
    const int k  = s * 32 + g * 8 + j;
    wp[idx] = (k < 200) ? f2bf(cw[k * 256 + oa]) : (unsigned short)0;
}

// ---------- prep 2: x -> bf16 transposed [b][y][x][i*8+ci] ----------
__global__ __launch_bounds__(256)
void prep_x(const float* __restrict__ x, unsigned short* __restrict__ xt) {
    __shared__ unsigned short tile[32 * 256];         // [xx][flat]
    const int t = threadIdx.x;                        // flat plane = i*8+ci
    const int b = blockIdx.x >> 5, y = blockIdx.x & 31;
    const float* src = x + (((size_t)((b << 8) + t)) << 10) + (y << 5);
    #pragma unroll
    for (int c = 0; c < 8; ++c) {
        float4 v = *(const float4*)(src + c * 4);
        tile[(c * 4 + 0) * 256 + t] = f2bf(v.x);
        tile[(c * 4 + 1) * 256 + t] = f2bf(v.y);
        tile[(c * 4 + 2) * 256 + t] = f2bf(v.z);
        tile[(c * 4 + 3) * 256 + t] = f2bf(v.w);
    }
    __syncthreads();
    unsigned short* dst = xt + ((size_t)blockIdx.x << 13);   // (b*32+y)*8192
    #pragma unroll
    for (int c = 0; c < 4; ++c) {
        const int chunk = t + c * 256;
        *(short8*)(dst + chunk * 8) = *(const short8*)(&tile[chunk * 8]);
    }
}

// ---------- main fused kernel ----------
__global__ __launch_bounds__(256, 3)
void capsule_mfma(const unsigned short* __restrict__ xt,
                  const unsigned short* __restrict__ wp,
                  const float* __restrict__ conv_b,
                  const float* __restrict__ biases,
                  float* __restrict__ out)
{
    __shared__ float votes[32 * 256];                 // 32 KB, col-swizzled
    __shared__ __align__(16) char ovl[14848];         // patch [32][232] bf16 / routing 8 KB

    const int t   = threadIdx.x;
    const int blk = blockIdx.x;
    const int b   = blk >> 10;
    const int pix = blk & 1023;
    const int h   = pix >> 5;
    const int w   = pix & 31;

    // ---- zero-pad patch k in [200,232) ----
    if (t < 128) {
        const int i = t >> 2, c = t & 3;
        *(float4*)(ovl + i * 464 + 400 + c * 16) = float4{0.f, 0.f, 0.f, 0.f};
    }

    // ---- stage patch: unit u = (p, i); lane loads 8 ci (16B) coalesced ----
    for (int u = t; u < 800; u += 256) {
        const int i = u & 31, p = u >> 5;
        const int ky = p / 5, kx = p - ky * 5;
        const int y = h + ky - 2, xx = w + kx - 2;
        short8 v = {0, 0, 0, 0, 0, 0, 0, 0};
        if ((unsigned)y < 32u && (unsigned)xx < 32u)
            v = *(const short8*)(xt + (((size_t)(((b << 5) + y) << 5) + xx) << 8) + i * 8);
        *(short8*)(ovl + i * 464 + p * 16) = v;       // patch[i][k=p*8..p*8+7]
    }

    // ---- conv: M=oa (A=W), N=i (B=patch), K=224 (7 steps of 32) ----
    const int l  = t & 63, wv = t >> 6;
    const int lm = l & 15, lg = l >> 4;

    f32x4 acc[4][2];
    #pragma unroll
    for (int mt = 0; mt < 4; ++mt)
        #pragma unroll
        for (int ti = 0; ti < 2; ++ti)
            acc[mt][ti] = (f32x4){0.f, 0.f, 0.f, 0.f};

    __syncthreads();   // patch ready

    // A-frag source: wp[s][g=lg][oa = wv*64 + mt*16 + lm][j]
    const unsigned short* wbase = wp + lg * 2048 + (((wv << 2) << 4) + lm) * 8;

    short8 a_cur[4], a_nxt[4];
    #pragma unroll
    for (int mt = 0; mt < 4; ++mt)
        a_cur[mt] = *(const short8*)(wbase + mt * 128);

    for (int s = 0; s < 7; ++s) {
        if (s < 6) {
            #pragma unroll
            for (int mt = 0; mt < 4; ++mt)
                a_nxt[mt] = *(const short8*)(wbase + (s + 1) * 8192 + mt * 128);
        }
        const short8 b0 = *(const short8*)(ovl + lm * 464 + s * 64 + lg * 16);
        const short8 b1 = *(const short8*)(ovl + (16 + lm) * 464 + s * 64 + lg * 16);
        #pragma unroll
        for (int mt = 0; mt < 4; ++mt) {
            acc[mt][0] = __builtin_amdgcn_mfma_f32_16x16x32_bf16(a_cur[mt], b0, acc[mt][0], 0, 0, 0);
            acc[mt][1] = __builtin_amdgcn_mfma_f32_16x16x32_bf16(a_cur[mt], b1, acc[mt][1], 0, 0, 0);
        }
        #pragma unroll
        for (int mt = 0; mt < 4; ++mt) a_cur[mt] = a_nxt[mt];
    }

    // ---- C-write: votes[i][oa] (+conv_b), XOR-swizzled cols ----
    #pragma unroll
    for (int mt = 0; mt < 4; ++mt) {
        const int oa0 = (((wv << 2) + mt) << 4) + (lg << 2);
        const float4 cb = *(const float4*)(conv_b + oa0);
        #pragma unroll
        for (int ti = 0; ti < 2; ++ti) {
            const int i = (ti << 4) + lm;
            float* dst = &votes[i * 256 + (oa0 ^ ((i & 7) << 2))];
            *(float4*)dst = float4{acc[mt][ti][0] + cb.x, acc[mt][ti][1] + cb.y,
                                   acc[mt][ti][2] + cb.z, acc[mt][ti][3] + cb.w};
        }
    }
    __syncthreads();   // votes visible; patch region free

    // ---- routing state in overlay ----
    float* route_s  = (float*)ovl;            // [32][32]
    float* logits_s = (float*)(ovl + 4096);   // [32][32]
    for (int idx = t; idx < 1024; idx += 256) {
        route_s[idx]  = 1.f / 33.f;           // softmax of 33 zeros
        logits_s[idx] = 0.f;
    }

    const int o_t = t >> 3, a_t = t & 7;
    const float bias_v = biases[t];
    float actv = 0.f;

    for (int it = 0; it < 3; ++it) {
        if (it > 0) {
            // leaky softmax per row i: 8 lanes per row, 4 o's each
            const int r = t >> 3, sub = t & 7;
            float e0 = logits_s[r * 32 + sub * 4 + 0];
            float e1 = logits_s[r * 32 + sub * 4 + 1];
            float e2 = logits_s[r * 32 + sub * 4 + 2];
            float e3 = logits_s[r * 32 + sub * 4 + 3];
            float mx = fmaxf(fmaxf(e0, e1), fmaxf(e2, e3));
            mx = fmaxf(mx, 0.f);              // leak logit
            #pragma unroll
            for (int d = 1; d < 8; d <<= 1)
                mx = fmaxf(mx, __shfl_xor(mx, d));
            e0 = expf(e0 - mx); e1 = expf(e1 - mx);
            e2 = expf(e2 - mx); e3 = expf(e3 - mx);
            float ssum = e0 + e1 + e2 + e3;
            #pragma unroll
            for (int d = 1; d < 8; d <<= 1)
                ssum += __shfl_xor(ssum, d);
            const float inv = 1.f / (ssum + expf(0.f - mx));
            route_s[r * 32 + sub * 4 + 0] = e0 * inv;
            route_s[r * 32 + sub * 4 + 1] = e1 * inv;
            route_s[r * 32 + sub * 4 + 2] = e2 * inv;
            route_s[r * 32 + sub * 4 + 3] = e3 * inv;
        }
        __syncthreads();

        // preact[o_t][a_t]
        float sacc = bias_v;
        #pragma unroll
        for (int i = 0; i < 32; ++i)
            sacc = fmaf(votes[i * 256 + (t ^ ((i & 7) << 2))], route_s[i * 32 + o_t], sacc);

        // squash over 8-atom group
        float ns = sacc * sacc;
        #pragma unroll
        for (int d = 1; d < 8; d <<= 1)
            ns += __shfl_xor(ns, d);
        const float norm = sqrtf(ns);
        actv = sacc * norm / (1.f + ns);

        if (it < 2) {
            #pragma unroll
            for (int i = 0; i < 32; ++i) {
                float d = votes[i * 256 + (t ^ ((i & 7) << 2))] * actv;
                d += __shfl_xor(d, 1);
                d += __shfl_xor(d, 2);
                d += __shfl_xor(d, 4);
                if (a_t == 0) logits_s[i * 32 + o_t] += d;
            }
            __syncthreads();
        }
    }

    out[(((size_t)(((b << 5) + o_t) << 10) + pix) << 3) + a_t] = actv;
}

extern "C" void kernel_launch(void* const* d_in, const int* in_sizes, int n_in,
                              void* d_out, int out_size, void* d_ws, size_t ws_size,
                              hipStream_t stream) {
    const float* x      = (const float*)d_in[0];
    const float* conv_w = (const float*)d_in[1];
    const float* conv_b = (const float*)d_in[2];
    const float* biases = (const float*)d_in[3];
    unsigned short* wp = (unsigned short*)d_ws;                     // 114,688 B
    unsigned short* xt = (unsigned short*)((char*)d_ws + 131072);   // 4 MB
    prep_w<<<dim3(224), dim3(256), 0, stream>>>(conv_w, wp);
    prep_x<<<dim3(256), dim3(256), 0, stream>>>(x, xt);
    capsule_mfma<<<dim3(8192), dim3(256), 0, stream>>>(xt, wp, conv_b, biases, (float*)d_out);
}

// Round 3
// 86.999 us; speedup vs baseline: 7.3682x; 2.1410x over previous
//
#include <hip/hip_runtime.h>
#include <math.h>

// ConvCapsule: bf16-MFMA per-pixel conv + fused 3-iter dynamic routing.
// R3: votes live in registers (one vote-row per thread after an LDS transpose);
// all 8-lane reductions via DPP (VALU pipe); routing LDS = route_T/logits_T only.
// LDS 20.5 KB, 4 blocks/CU.

using short8 = __attribute__((ext_vector_type(8))) short;
using f32x4  = __attribute__((ext_vector_type(4))) float;

__device__ __forceinline__ unsigned short f2bf(float f) {
    unsigned u = __float_as_uint(f);
    return (unsigned short)((u + 0x7fffu + ((u >> 16) & 1u)) >> 16);  // RNE
}

// DPP helpers: 8-lane-group reductions (lanes differing in bits 0..2).
template<int CTRL>
__device__ __forceinline__ float dpp_movf(float x) {
    return __int_as_float(__builtin_amdgcn_update_dpp(
        0, __float_as_int(x), CTRL, 0xF, 0xF, true));
}
__device__ __forceinline__ float sum8(float x) {     // xor1, xor2, xor4(in-8)
    x += dpp_movf<0xB1>(x);    // quad_perm [1,0,3,2]
    x += dpp_movf<0x4E>(x);    // quad_perm [2,3,0,1]
    x += dpp_movf<0x141>(x);   // row_half_mirror
    return x;
}
__device__ __forceinline__ float max8(float x) {
    x = fmaxf(x, dpp_movf<0xB1>(x));
    x = fmaxf(x, dpp_movf<0x4E>(x));
    x = fmaxf(x, dpp_movf<0x141>(x));
    return x;
}

// ---------- prep 1: W -> bf16, [s][g][oa][j], k = s*32+g*8+j ----------
__global__ __launch_bounds__(256)
void prep_w(const float* __restrict__ cw, unsigned short* __restrict__ wp) {
    const int idx = blockIdx.x * 256 + threadIdx.x;   // 57344 total
    const int j  = idx & 7;
    const int oa = (idx >> 3) & 255;
    const int g  = (idx >> 11) & 3;
    const int s  = idx >> 13;
    const int k  = s * 32 + g * 8 + j;
    wp[idx] = (k < 200) ? f2bf(cw[k * 256 + oa]) : (unsigned short)0;
}

// ---------- prep 2: x -> bf16 transposed [b][y][x][i*8+ci] ----------
__global__ __launch_bounds__(256)
void prep_x(const float* __restrict__ x, unsigned short* __restrict__ xt) {
    __shared__ unsigned short tile[32 * 256];         // [xx][flat]
    const int t = threadIdx.x;                        // flat plane = i*8+ci
    const int b = blockIdx.x >> 5, y = blockIdx.x & 31;
    const float* src = x + (((size_t)((b << 8) + t)) << 10) + (y << 5);
    #pragma unroll
    for (int c = 0; c < 8; ++c) {
        float4 v = *(const float4*)(src + c * 4);
        tile[(c * 4 + 0) * 256 + t] = f2bf(v.x);
        tile[(c * 4 + 1) * 256 + t] = f2bf(v.y);
        tile[(c * 4 + 2) * 256 + t] = f2bf(v.z);
        tile[(c * 4 + 3) * 256 + t] = f2bf(v.w);
    }
    __syncthreads();
    unsigned short* dst = xt + ((size_t)blockIdx.x << 13);   // (b*32+y)*8192
    #pragma unroll
    for (int c = 0; c < 4; ++c) {
        const int chunk = t + c * 256;
        *(short8*)(dst + chunk * 8) = *(const short8*)(&tile[chunk * 8]);
    }
}

// ---------- main fused kernel ----------
__global__ __launch_bounds__(256, 4)
void capsule_mfma(const unsigned short* __restrict__ xt,
                  const unsigned short* __restrict__ wp,
                  const float* __restrict__ conv_b,
                  const float* __restrict__ biases,
                  float* __restrict__ out)
{
    // Overlaid LDS phases:
    //   A: patch  [32 i][232 k] bf16 (14848 B)   — conv B-operand
    //   B: vtr    per-wave float[64][20] (4*5120 = 20480 B) — C transpose medium
    //   C: route_T float[32][36] @0 ; logits_T float[32][36] @4608 (9216 B)
    __shared__ __align__(16) char lds[20480];
    float* route_T  = (float*)lds;
    float* logits_T = (float*)(lds + 4608);

    const int t   = threadIdx.x;
    const int blk = blockIdx.x;
    const int b   = blk >> 10;
    const int pix = blk & 1023;
    const int h   = pix >> 5;
    const int w   = pix & 31;

    // ---- zero-pad patch k in [200,232) ----
    if (t < 128) {
        const int i = t >> 2, c = t & 3;
        *(f32x4*)(lds + i * 464 + 400 + c * 16) = (f32x4){0.f, 0.f, 0.f, 0.f};
    }

    // ---- stage patch: unit u = (p, i); lane loads 8 ci (16B) coalesced ----
    for (int u = t; u < 800; u += 256) {
        const int i = u & 31, p = u >> 5;
        const int ky = p / 5, kx = p - ky * 5;
        const int y = h + ky - 2, xx = w + kx - 2;
        short8 v = {0, 0, 0, 0, 0, 0, 0, 0};
        if ((unsigned)y < 32u && (unsigned)xx < 32u)
            v = *(const short8*)(xt + (((size_t)(((b << 5) + y) << 5) + xx) << 8) + i * 8);
        *(short8*)(lds + i * 464 + p * 16) = v;       // patch[i][k=p*8..p*8+7]
    }

    // ---- conv: M=oa (A=W), N=i (B=patch), K=224 (7 steps of 32) ----
    const int l  = t & 63, wv = t >> 6;
    const int lm = l & 15, lg = l >> 4;

    f32x4 acc[4][2];
    #pragma unroll
    for (int mt = 0; mt < 4; ++mt)
        #pragma unroll
        for (int ti = 0; ti < 2; ++ti)
            acc[mt][ti] = (f32x4){0.f, 0.f, 0.f, 0.f};

    __syncthreads();   // patch ready

    // A-frag source: wp[s][g=lg][oa = wv*64 + mt*16 + lm][j]
    const unsigned short* wbase = wp + lg * 2048 + (((wv << 2) << 4) + lm) * 8;

    short8 a_cur[4], a_nxt[4];
    #pragma unroll
    for (int mt = 0; mt < 4; ++mt)
        a_cur[mt] = *(const short8*)(wbase + mt * 128);

    for (int s = 0; s < 7; ++s) {
        if (s < 6) {
            #pragma unroll
            for (int mt = 0; mt < 4; ++mt)
                a_nxt[mt] = *(const short8*)(wbase + (s + 1) * 8192 + mt * 128);
        }
        const short8 b0 = *(const short8*)(lds + lm * 464 + s * 64 + lg * 16);
        const short8 b1 = *(const short8*)(lds + (16 + lm) * 464 + s * 64 + lg * 16);
        #pragma unroll
        for (int mt = 0; mt < 4; ++mt) {
            acc[mt][0] = __builtin_amdgcn_mfma_f32_16x16x32_bf16(a_cur[mt], b0, acc[mt][0], 0, 0, 0);
            acc[mt][1] = __builtin_amdgcn_mfma_f32_16x16x32_bf16(a_cur[mt], b1, acc[mt][1], 0, 0, 0);
        }
        #pragma unroll
        for (int mt = 0; mt < 4; ++mt) a_cur[mt] = a_nxt[mt];
    }

    __syncthreads();   // all waves done reading patch; lds reusable

    // ---- transpose C through per-wave LDS region: thread t gets v[i]=vote[oa=t][i] ----
    // MFMA C layout (16x16x32): thread(lg,lm) holds C[row=oa_local=mt*16+lg*4+r][col=i=lm or 16+lm]
    float v[32];
    float* vtr = (float*)(lds) + wv * 1280;           // [64][20] floats per wave
    #pragma unroll
    for (int ti = 0; ti < 2; ++ti) {
        #pragma unroll
        for (int mt = 0; mt < 4; ++mt)
            #pragma unroll
            for (int r = 0; r < 4; ++r)
                vtr[(mt * 16 + lg * 4 + r) * 20 + lm] = acc[mt][ti][r];
        __syncthreads();
        #pragma unroll
        for (int c = 0; c < 4; ++c) {
            const f32x4 vv = *(const f32x4*)(vtr + l * 20 + c * 4);
            v[ti * 16 + c * 4 + 0] = vv[0];
            v[ti * 16 + c * 4 + 1] = vv[1];
            v[ti * 16 + c * 4 + 2] = vv[2];
            v[ti * 16 + c * 4 + 3] = vv[3];
        }
        __syncthreads();
    }

    // fold conv bias; iteration-0 route is uniformly 1/33 -> just need rowsum
    const float cb = conv_b[t];
    float rowsum = 0.f;
    #pragma unroll
    for (int i = 0; i < 32; ++i) { v[i] += cb; rowsum += v[i]; }

    const int o_t = t >> 3, a_t = t & 7;
    const float bias_v = biases[t];
    float actv = 0.f;

    #pragma unroll
    for (int it = 0; it < 3; ++it) {
        // ---- preact[o_t][a_t] ----
        float pre;
        if (it == 0) {
            pre = fmaf(rowsum, 1.f / 33.f, bias_v);
        } else {
            pre = bias_v;
            const float* rrow = route_T + o_t * 36;
            #pragma unroll
            for (int c = 0; c < 8; ++c) {
                const f32x4 rv = *(const f32x4*)(rrow + c * 4);   // broadcast (8 lanes/addr)
                pre = fmaf(v[c * 4 + 0], rv[0], pre);
                pre = fmaf(v[c * 4 + 1], rv[1], pre);
                pre = fmaf(v[c * 4 + 2], rv[2], pre);
                pre = fmaf(v[c * 4 + 3], rv[3], pre);
            }
        }

        // ---- squash over the 8-atom group (DPP) ----
        const float ns = sum8(pre * pre);
        actv = pre * sqrtf(ns) / (1.f + ns);

        if (it < 2) {
            // ---- logits[i][o_t] += sum_a v[i]*act (DPP a-reduce, a==0 lane writes) ----
            float dsum[32];
            #pragma unroll
            for (int i = 0; i < 32; ++i)
                dsum[i] = sum8(v[i] * actv);
            if (a_t == 0) {
                float* lrow = logits_T + o_t * 36;
                #pragma unroll
                for (int c = 0; c < 8; ++c) {
                    f32x4 cur = (it == 0) ? (f32x4){0.f, 0.f, 0.f, 0.f}
                                          : *(const f32x4*)(lrow + c * 4);
                    cur[0] += dsum[c * 4 + 0];
                    cur[1] += dsum[c * 4 + 1];
                    cur[2] += dsum[c * 4 + 2];
                    cur[3] += dsum[c * 4 + 3];
                    *(f32x4*)(lrow + c * 4) = cur;
                }
            }
            __syncthreads();

            // ---- leaky softmax over o for row i=o_t (8 sub-lanes x 4 o's) ----
            const int r = o_t, sub = a_t;
            float e0 = logits_T[(sub * 4 + 0) * 36 + r];
            float e1 = logits_T[(sub * 4 + 1) * 36 + r];
            float e2 = logits_T[(sub * 4 + 2) * 36 + r];
            float e3 = logits_T[(sub * 4 + 3) * 36 + r];
            float mx = fmaxf(fmaxf(e0, e1), fmaxf(e2, e3));
            mx = max8(fmaxf(mx, 0.f));                // include leak logit 0
            e0 = __expf(e0 - mx); e1 = __expf(e1 - mx);
            e2 = __expf(e2 - mx); e3 = __expf(e3 - mx);
            const float ssum = sum8(e0 + e1 + e2 + e3) + __expf(-mx);
            const float inv = 1.f / ssum;
            route_T[(sub * 4 + 0) * 36 + r] = e0 * inv;
            route_T[(sub * 4 + 1) * 36 + r] = e1 * inv;
            route_T[(sub * 4 + 2) * 36 + r] = e2 * inv;
            route_T[(sub * 4 + 3) * 36 + r] = e3 * inv;
            __syncthreads();
        }
    }

    // out[b][o][h][w][a]
    out[(((size_t)(((b << 5) + o_t) << 10) + pix) << 3) + a_t] = actv;
}

extern "C" void kernel_launch(void* const* d_in, const int* in_sizes, int n_in,
                              void* d_out, int out_size, void* d_ws, size_t ws_size,
                              hipStream_t stream) {
    const float* x      = (const float*)d_in[0];
    const float* conv_w = (const float*)d_in[1];
    const float* conv_b = (const float*)d_in[2];
    const float* biases = (const float*)d_in[3];
    unsigned short* wp = (unsigned short*)d_ws;                     // 114,688 B
    unsigned short* xt = (unsigned short*)((char*)d_ws + 131072);   // 4 MB
    prep_w<<<dim3(224), dim3(256), 0, stream>>>(conv_w, wp);
    prep_x<<<dim3(256), dim3(256), 0, stream>>>(x, xt);
    capsule_mfma<<<dim3(8192), dim3(256), 0, stream>>>(xt, wp, conv_b, biases, (float*)d_out);
}